// Round 23
// baseline (94.829 us; speedup 1.0000x reference)
//
#include <hip/hip_runtime.h>

#define BB 2
#define NN 2048
#define DD 256
#define HH 8
#define HD 32
#define EPS 1e-5f
#define L2E 1.4426950408889634f

typedef __attribute__((ext_vector_type(8))) short bf16x8;
typedef __attribute__((ext_vector_type(4))) float f32x4;
typedef __attribute__((ext_vector_type(2))) float f32x2;
typedef __attribute__((ext_vector_type(8))) unsigned short u16x8;

__device__ __forceinline__ float lky(float z){ return fmaxf(z, 0.2f*z); }

// Raw hardware exp2: args <= ~0 here; flush-to-zero below -126 is the right answer.
__device__ __forceinline__ float exp2raw(float x){
    float r;
    asm("v_exp_f32 %0, %1" : "=v"(r) : "v"(x));
    return r;
}

__device__ __forceinline__ ushort f2bf(float f){
    union{ float f; unsigned u; } c; c.f = f;
    unsigned r = c.u + 0x7fffu + ((c.u >> 16) & 1u);
    return (ushort)(r >> 16);
}
__device__ __forceinline__ float bf2f(ushort u){
    union{ unsigned u; float f; } c; c.u = ((unsigned)u) << 16; return c.f;
}
__device__ __forceinline__ unsigned cvtpk(float lo, float hi){
    unsigned r;
    asm("v_cvt_pk_bf16_f32 %0, %1, %2" : "=v"(r) : "v"(lo), "v"(hi));
    return r;
}

// K0: blocks 0-7: uqkb bf16 + cq/ck (log2e-scaled); 8-71: WoT; 72-135: WvT.
__global__ void k_prep(const float* __restrict__ Wq, const float* __restrict__ bq,
                       const float* __restrict__ Wk, const float* __restrict__ bk,
                       const float* __restrict__ aa, const float* __restrict__ Wo,
                       const float* __restrict__ Wv,
                       ushort* __restrict__ uqkb, float* __restrict__ cq,
                       float* __restrict__ ck, ushort* __restrict__ WoT,
                       ushort* __restrict__ WvT){
    int t = threadIdx.x;
    if(blockIdx.x < 8){
        int h = blockIdx.x;
        int d = t;
        float accq = 0.f, acck = 0.f;
        #pragma unroll
        for(int k=0; k<HD; k++){
            accq += Wq[(size_t)d*DD + h*HD + k] * aa[h*2*HD + k];
            acck += Wk[(size_t)d*DD + h*HD + k] * aa[h*2*HD + HD + k];
        }
        uqkb[h*DD + d]     = f2bf(accq * L2E);
        uqkb[(8+h)*DD + d] = f2bf(acck * L2E);
        __shared__ float red[64];
        if(d < HD){
            red[d]      = bq[h*HD+d]*aa[h*2*HD+d];
            red[32+d]   = bk[h*HD+d]*aa[h*2*HD+HD+d];
        }
        __syncthreads();
        if(d==0){ float s=0.f; for(int k=0;k<32;k++) s+=red[k];    cq[h]=s*L2E; }
        if(d==1){ float s=0.f; for(int k=0;k<32;k++) s+=red[32+k]; ck[h]=s*L2E; }
    } else if(blockIdx.x < 72){
        int blk = blockIdx.x - 8;     // 0..63
        int wv = t>>6, l = t&63;
        int tile = blk*4 + wv;        // 0..255
        int tr = (tile>>4)*16, tc = (tile&15)*16;
        #pragma unroll
        for(int e=0;e<4;e++){
            int idx = l*4+e;
            int kk = tr + (idx>>4);
            int nn = tc + (idx&15);
            WoT[(size_t)nn*DD + kk] = f2bf(Wo[(size_t)kk*DD + nn]);
        }
    } else {
        int blk = blockIdx.x - 72;    // 0..63
        int wv = t>>6, l = t&63;
        int tile = blk*4 + wv;
        int tr = (tile>>4)*16, tc = (tile&15)*16;
        #pragma unroll
        for(int e=0;e<4;e++){
            int idx = l*4+e;
            int kk = tr + (idx>>4);
            int nn = tc + (idx&15);
            WvT[(size_t)nn*DD + kk] = f2bf(Wv[(size_t)kk*DD + nn]);
        }
    }
}

// K1: 16 rows/block, full MFMA: scores (wave0) + v-projection GEMM (all waves).
__global__ __launch_bounds__(256, 4)
void k_sqskv(const float* __restrict__ x, const float* __restrict__ bv,
             const ushort* __restrict__ uqkb, const ushort* __restrict__ WvT,
             const float* __restrict__ cq, const float* __restrict__ ck,
             ushort* __restrict__ vT, float* __restrict__ sq,
             float* __restrict__ skH){
    __shared__ ushort xb[16][264];   // bf16 x rows
    int t = threadIdx.x;
    int r0 = blockIdx.x * 16;
    int b  = r0 >> 11;
    int j0 = r0 & (NN-1);
    #pragma unroll
    for(int i=0;i<16;i++) xb[i][t] = f2bf(x[((size_t)r0+i)*DD + t]);
    __syncthreads();

    int wv = t>>6, l = t&63, lr = l&15, kg = l>>4;

    // wave 0: scores: C[i][n] = sum_k xb[i][k]*uqkb[n][k]  (M=16 real rows)
    if(wv == 0){
        f32x4 acc = (f32x4){0.f,0.f,0.f,0.f};
        #pragma unroll
        for(int ks=0; ks<8; ks++){
            bf16x8 a = *reinterpret_cast<const bf16x8*>(&xb[lr][ks*32 + kg*8]);
            bf16x8 bb = *reinterpret_cast<const bf16x8*>(uqkb + (size_t)lr*DD + ks*32 + kg*8);
            acc = __builtin_amdgcn_mfma_f32_16x16x32_bf16(a, bb, acc, 0,0,0);
        }
        #pragma unroll
        for(int rg=0; rg<4; rg++){
            int i = kg*4 + rg;
            int R = r0 + i;
            float vsc = acc[rg];
            if(lr < 8) sq[(size_t)R*HH + lr] = vsc + cq[lr];
            else       skH[((size_t)b*NN + (R & (NN-1)))*HH + (lr-8)] = vsc + ck[lr-8];
        }
    }

    // v GEMM: wave wv -> n-tiles 4wv..4wv+3; C[i][n]; store vT[b][n][j0+i]
    f32x4 vacc[4];
    #pragma unroll
    for(int q=0;q<4;q++) vacc[q] = (f32x4){0.f,0.f,0.f,0.f};
    #pragma unroll
    for(int ks=0; ks<8; ks++){
        bf16x8 a = *reinterpret_cast<const bf16x8*>(&xb[lr][ks*32 + kg*8]);
        #pragma unroll
        for(int q=0;q<4;q++){
            int n0 = (wv*4+q)*16;
            bf16x8 bb = *reinterpret_cast<const bf16x8*>(WvT + (size_t)(n0+lr)*DD + ks*32 + kg*8);
            vacc[q] = __builtin_amdgcn_mfma_f32_16x16x32_bf16(a, bb, vacc[q], 0,0,0);
        }
    }
    #pragma unroll
    for(int q=0;q<4;q++){
        int n = (wv*4+q)*16 + lr;
        float bvn = bv[n];
        ushort4 pk;
        pk.x = f2bf(vacc[q][0] + bvn);
        pk.y = f2bf(vacc[q][1] + bvn);
        pk.z = f2bf(vacc[q][2] + bvn);
        pk.w = f2bf(vacc[q][3] + bvn);
        *reinterpret_cast<ushort4*>(&vT[((size_t)b*DD + n)*NN + j0 + kg*4]) = pk;
    }
}

// K1b: Mk[b][h] = max_j skH[b][j][h]
__global__ void k_maxsk(const float* __restrict__ skH, float* __restrict__ Mk){
    int b = blockIdx.x >> 3, h = blockIdx.x & 7;
    int t = threadIdx.x;
    float m = -1e30f;
    for(int j=t; j<NN; j+=256) m = fmaxf(m, skH[((size_t)b*NN + j)*HH + h]);
    #pragma unroll
    for(int off=32; off>=1; off>>=1) m = fmaxf(m, __shfl_xor(m, off));
    __shared__ float red[4];
    if((t&63)==0) red[t>>6] = m;
    __syncthreads();
    if(t==0) Mk[blockIdx.x] = fmaxf(fmaxf(red[0],red[1]), fmaxf(red[2],red[3]));
}

// K2: 4 rows/block (halves skH L2 traffic), raw adj in, Madj + adj-bitmask out.
__global__ void k_denom(const int* __restrict__ adj, const float* __restrict__ sq,
                        const float* __restrict__ skH, const float* __restrict__ Mk,
                        float* __restrict__ Madj, unsigned* __restrict__ adjm){
    int r0 = blockIdx.x*4;          // rows r0..r0+3 (same b)
    int b = r0 >> 11;
    int t = threadIdx.x;
    int w = t>>6, l = t&63;
    float sqr[4][HH], Mr[4][HH], sr[4][HH];
    #pragma unroll
    for(int rr=0;rr<4;rr++){
        float4 a0 = *reinterpret_cast<const float4*>(&sq[(size_t)(r0+rr)*HH]);
        float4 a1 = *reinterpret_cast<const float4*>(&sq[(size_t)(r0+rr)*HH+4]);
        sqr[rr][0]=a0.x; sqr[rr][1]=a0.y; sqr[rr][2]=a0.z; sqr[rr][3]=a0.w;
        sqr[rr][4]=a1.x; sqr[rr][5]=a1.y; sqr[rr][6]=a1.z; sqr[rr][7]=a1.w;
    }
    {
        float4 m0 = *reinterpret_cast<const float4*>(&Mk[b*HH]);
        float4 m1 = *reinterpret_cast<const float4*>(&Mk[b*HH+4]);
        float mk[8] = {m0.x,m0.y,m0.z,m0.w,m1.x,m1.y,m1.z,m1.w};
        #pragma unroll
        for(int rr=0;rr<4;rr++)
            #pragma unroll
            for(int h=0;h<HH;h++){
                Mr[rr][h] = lky(sqr[rr][h]+mk[h]);
                sr[rr][h] = 0.f;
            }
    }
    for(int j0=0; j0<NN; j0+=256){
        int j = j0 + t;
        int av[4];
        #pragma unroll
        for(int rr=0;rr<4;rr++) av[rr] = adj[((size_t)(r0+rr))*NN + j];
        {
            int cw = (j0 >> 5) + w*2;
            #pragma unroll
            for(int rr=0;rr<4;rr++){
                unsigned long long mb = __ballot(av[rr] != 0);
                if(l == 0)  adjm[((size_t)(r0+rr))*64 + cw]     = (unsigned)mb;
                if(l == 32) adjm[((size_t)(r0+rr))*64 + cw + 1] = (unsigned)(mb >> 32);
            }
        }
        float4 v0 = *reinterpret_cast<const float4*>(&skH[((size_t)b*NN + j)*HH]);
        float4 v1 = *reinterpret_cast<const float4*>(&skH[((size_t)b*NN + j)*HH+4]);
        float sk[8] = {v0.x,v0.y,v0.z,v0.w,v1.x,v1.y,v1.z,v1.w};
        #pragma unroll
        for(int rr=0;rr<4;rr++){
            #pragma unroll
            for(int h=0; h<HH; h++){
                float e = exp2raw(lky(sqr[rr][h]+sk[h]) - Mr[rr][h]);
                sr[rr][h] += av[rr] ? e : 0.f;
            }
        }
    }
    #pragma unroll
    for(int rr=0;rr<4;rr++)
        #pragma unroll
        for(int h=0;h<HH;h++){
            #pragma unroll
            for(int off=32; off>=1; off>>=1)
                sr[rr][h] += __shfl_xor(sr[rr][h], off);
        }
    __shared__ float red[4][32];
    if(l==0){
        #pragma unroll
        for(int rr=0;rr<4;rr++)
            #pragma unroll
            for(int h=0;h<HH;h++) red[w][rr*8+h]=sr[rr][h];
    }
    __syncthreads();
    if(t < 32){
        float s = red[0][t]+red[1][t]+red[2][t]+red[3][t];
        int rr = t >> 3, h = t & 7;
        Madj[(size_t)(r0+rr)*HH + h] = Mr[rr][h] + log2f(s);
    }
}

// K3: verified structure; JC=4.
#define TI 32
#define JT 32
#define JC 4
#define JPC (NN/JC)   // 512

__global__ __launch_bounds__(256, 4)
void k_attn(const unsigned* __restrict__ adjm, const float* __restrict__ sq,
            const float* __restrict__ skH, const float* __restrict__ Madj,
            const ushort* __restrict__ vT, float* __restrict__ meanw,
            ushort* __restrict__ attp){
    __shared__ __align__(16) char smem[40960];
    ushort (*wLDS)[TI][40] = (ushort (*)[TI][40])smem;           // [h][i][j] 20480B
    ushort (*vLDS)[40]     = (ushort (*)[40])(smem + 20480);     // [d][j]    20480B
    float* fb = (float*)smem;                                     // epilogue 32KB

    int t  = threadIdx.x;
    int it = blockIdx.x;
    int b  = blockIdx.y;
    int jc = blockIdx.z;
    int i0 = it*TI;
    int R0 = b*NN + i0;

    int ia = t >> 4;
    int jp = t & 15;
    int jj = jp*2;

    float sq1[8], sq2[8], M1[8], M2[8];
    {
        float4 a0 = *reinterpret_cast<const float4*>(&sq[(size_t)(R0+ia)*HH]);
        float4 a1 = *reinterpret_cast<const float4*>(&sq[(size_t)(R0+ia)*HH+4]);
        float4 b0 = *reinterpret_cast<const float4*>(&sq[(size_t)(R0+16+ia)*HH]);
        float4 b1 = *reinterpret_cast<const float4*>(&sq[(size_t)(R0+16+ia)*HH+4]);
        sq1[0]=a0.x; sq1[1]=a0.y; sq1[2]=a0.z; sq1[3]=a0.w;
        sq1[4]=a1.x; sq1[5]=a1.y; sq1[6]=a1.z; sq1[7]=a1.w;
        sq2[0]=b0.x; sq2[1]=b0.y; sq2[2]=b0.z; sq2[3]=b0.w;
        sq2[4]=b1.x; sq2[5]=b1.y; sq2[6]=b1.z; sq2[7]=b1.w;
        float4 c0 = *reinterpret_cast<const float4*>(&Madj[(size_t)(R0+ia)*HH]);
        float4 c1 = *reinterpret_cast<const float4*>(&Madj[(size_t)(R0+ia)*HH+4]);
        float4 d0 = *reinterpret_cast<const float4*>(&Madj[(size_t)(R0+16+ia)*HH]);
        float4 d1 = *reinterpret_cast<const float4*>(&Madj[(size_t)(R0+16+ia)*HH+4]);
        M1[0]=c0.x; M1[1]=c0.y; M1[2]=c0.z; M1[3]=c0.w;
        M1[4]=c1.x; M1[5]=c1.y; M1[6]=c1.z; M1[7]=c1.w;
        M2[0]=d0.x; M2[1]=d0.y; M2[2]=d0.z; M2[3]=d0.w;
        M2[4]=d1.x; M2[5]=d1.y; M2[6]=d1.z; M2[7]=d1.w;
    }

    int wid = t >> 6;
    int l   = t & 63;
    int lr  = l & 15;
    int kg  = l >> 4;

    f32x4 acc[2][2][2];
    #pragma unroll
    for(int hh=0;hh<2;hh++)
        #pragma unroll
        for(int mi=0;mi<2;mi++)
            #pragma unroll
            for(int ni=0;ni<2;ni++) acc[hh][mi][ni] = (f32x4){0.f,0.f,0.f,0.f};

    const ushort* vsrc = vT + ((size_t)b*DD + t)*NN;
    const float* skbase = skH + (size_t)b*NN*HH;
    const unsigned* mArow = adjm + (size_t)(R0+ia)*64 + jc*16;
    const unsigned* mBrow = adjm + (size_t)(R0+16+ia)*64 + jc*16;

    for(int jt=0; jt<JPC/JT; jt++){
        int jb = jc*JPC + jt*JT;

        __syncthreads();   // prev tile MFMA done reading wLDS/vLDS

        // stage v to LDS (loads AFTER barrier — proven placement)
        {
            const ushort* src = vsrc + jb;
            u16x8 v0 = *reinterpret_cast<const u16x8*>(src);
            u16x8 v1 = *reinterpret_cast<const u16x8*>(src+8);
            u16x8 v2 = *reinterpret_cast<const u16x8*>(src+16);
            u16x8 v3 = *reinterpret_cast<const u16x8*>(src+24);
            *reinterpret_cast<u16x8*>(&vLDS[t][0])  = v0;
            *reinterpret_cast<u16x8*>(&vLDS[t][8])  = v1;
            *reinterpret_cast<u16x8*>(&vLDS[t][16]) = v2;
            *reinterpret_cast<u16x8*>(&vLDS[t][24]) = v3;
        }

        // Phase A
        {
            float4 p0 = *reinterpret_cast<const float4*>(&skbase[(size_t)(jb+jj)*HH]);
            float4 p1 = *reinterpret_cast<const float4*>(&skbase[(size_t)(jb+jj)*HH+4]);
            float4 q0 = *reinterpret_cast<const float4*>(&skbase[(size_t)(jb+jj+1)*HH]);
            float4 q1 = *reinterpret_cast<const float4*>(&skbase[(size_t)(jb+jj+1)*HH+4]);
            unsigned wA = mArow[jt];
            unsigned wB = mBrow[jt];
            float ska[8] = {p0.x,p0.y,p0.z,p0.w,p1.x,p1.y,p1.z,p1.w};
            float skb[8] = {q0.x,q0.y,q0.z,q0.w,q1.x,q1.y,q1.z,q1.w};
            unsigned bA = (wA >> jj) & 3u;
            unsigned bB = (wB >> jj) & 3u;
            f32x2 wsA = {0.f,0.f}, wsB = {0.f,0.f};
            #pragma unroll
            for(int h=0; h<HH; h++){
                float eA0 = exp2raw(lky(sq1[h]+ska[h]) - M1[h]);
                float eA1 = exp2raw(lky(sq1[h]+skb[h]) - M1[h]);
                float eB0 = exp2raw(lky(sq2[h]+ska[h]) - M2[h]);
                float eB1 = exp2raw(lky(sq2[h]+skb[h]) - M2[h]);
                float w00 = (bA&1u) ? eA0 : 0.f;
                float w01 = (bA&2u) ? eA1 : 0.f;
                float w10 = (bB&1u) ? eB0 : 0.f;
                float w11 = (bB&2u) ? eB1 : 0.f;
                wsA += (f32x2){w00, w01};
                wsB += (f32x2){w10, w11};
                *reinterpret_cast<unsigned*>(&wLDS[h][ia][jj])    = cvtpk(w00, w01);
                *reinterpret_cast<unsigned*>(&wLDS[h][16+ia][jj]) = cvtpk(w10, w11);
            }
            wsA *= 0.125f; wsB *= 0.125f;
            *reinterpret_cast<f32x2*>(&meanw[((size_t)(R0+ia))*NN + jb + jj])    = wsA;
            *reinterpret_cast<f32x2*>(&meanw[((size_t)(R0+16+ia))*NN + jb + jj]) = wsB;
        }
        __syncthreads();

        // Phase B: MFMA
        #pragma unroll
        for(int hh=0; hh<2; hh++){
            int h = wid*2 + hh;
            bf16x8 a0 = *reinterpret_cast<const bf16x8*>(&wLDS[h][lr][kg*8]);
            bf16x8 a1 = *reinterpret_cast<const bf16x8*>(&wLDS[h][16+lr][kg*8]);
            bf16x8 b0 = *reinterpret_cast<const bf16x8*>(&vLDS[h*HD + lr][kg*8]);
            bf16x8 b1 = *reinterpret_cast<const bf16x8*>(&vLDS[h*HD + 16 + lr][kg*8]);
            acc[hh][0][0] = __builtin_amdgcn_mfma_f32_16x16x32_bf16(a0, b0, acc[hh][0][0], 0,0,0);
            acc[hh][0][1] = __builtin_amdgcn_mfma_f32_16x16x32_bf16(a0, b1, acc[hh][0][1], 0,0,0);
            acc[hh][1][0] = __builtin_amdgcn_mfma_f32_16x16x32_bf16(a1, b0, acc[hh][1][0], 0,0,0);
            acc[hh][1][1] = __builtin_amdgcn_mfma_f32_16x16x32_bf16(a1, b1, acc[hh][1][1], 0,0,0);
        }
    }

    // Epilogue: XOR-swizzled fb, coalesced bf16 stores
    __syncthreads();
    #pragma unroll
    for(int hh=0;hh<2;hh++)
        #pragma unroll
        for(int mi=0;mi<2;mi++)
            #pragma unroll
            for(int ni=0;ni<2;ni++)
                #pragma unroll
                for(int rg=0; rg<4; rg++){
                    int i = mi*16 + kg*4 + rg;
                    int d = (wid*2+hh)*HD + ni*16 + lr;
                    fb[i*256 + (d ^ ((i&7)<<2))] = acc[hh][mi][ni][rg];
                }
    __syncthreads();
    {
        int i  = t >> 3;              // 0..31 row; 8 threads per row
        int d0 = (t & 7) * 32;        // contiguous 512B per row across 8 threads
        int swz = (i & 7) << 2;
        size_t orow = ((size_t)(jc*BB + b)*NN + i0 + i)*DD + d0;
        #pragma unroll
        for(int qq=0; qq<4; qq++){
            float4 f0 = *reinterpret_cast<const float4*>(&fb[i*256 + ((d0 + qq*8)     ^ swz)]);
            float4 f1 = *reinterpret_cast<const float4*>(&fb[i*256 + ((d0 + qq*8 + 4) ^ swz)]);
            uint4 pk;
            pk.x = cvtpk(f0.x, f0.y); pk.y = cvtpk(f0.z, f0.w);
            pk.z = cvtpk(f1.x, f1.y); pk.w = cvtpk(f1.z, f1.w);
            *reinterpret_cast<uint4*>(&attp[orow + qq*8]) = pk;
        }
    }
}

// K4: out = LN( (sum attp) @ Wo + bo + x ) — MFMA GEMM, 16 real rows/block.
__global__ __launch_bounds__(256, 2)
void k_out(const ushort* __restrict__ attp, const float* __restrict__ x,
           const ushort* __restrict__ WoT, const float* __restrict__ bo,
           const float* __restrict__ g, const float* __restrict__ bln,
           float* __restrict__ out){
    __shared__ ushort ab[16][264];   // bf16 attended, 16 real rows
    __shared__ float fbo[16][260];   // GEMM result / LN scratch
    __shared__ float ps[16][16][2];
    __shared__ float muL[16], rsL[16];
    int t = threadIdx.x;
    int r0 = blockIdx.x*16;
    int b  = r0 >> 11;
    int j0 = r0 & (NN-1);

    // sum partials -> ab bf16 (two row-groups of 8)
    #pragma unroll
    for(int rp=0; rp<2; rp++){
        int rr = rp*8 + (t >> 5);
        int d0 = (t & 31) * 8;
        float s8[8];
        #pragma unroll
        for(int e=0;e<8;e++) s8[e]=0.f;
        #pragma unroll
        for(int jc=0; jc<JC; jc++){
            u16x8 v = *reinterpret_cast<const u16x8*>(&attp[((size_t)(jc*BB + b)*NN + j0 + rr)*DD + d0]);
            #pragma unroll
            for(int e=0;e<8;e++) s8[e] += bf2f(v[e]);
        }
        u16x8 pack;
        #pragma unroll
        for(int e=0;e<8;e++) pack[e] = f2bf(s8[e]);
        *reinterpret_cast<u16x8*>(&ab[rr][d0]) = pack;
    }
    __syncthreads();

    // MFMA GEMM: wave wv handles n-tiles 4wv..4wv+3, M=16 all-real
    {
        int wv = t>>6, l = t&63, lr = l&15, kg = l>>4;
        f32x4 acc0 = (f32x4){0.f,0.f,0.f,0.f};
        f32x4 acc1 = (f32x4){0.f,0.f,0.f,0.f};
        f32x4 acc2 = (f32x4){0.f,0.f,0.f,0.f};
        f32x4 acc3 = (f32x4){0.f,0.f,0.f,0.f};
        #pragma unroll
        for(int ks=0; ks<8; ks++){
            bf16x8 a = *reinterpret_cast<const bf16x8*>(&ab[lr][ks*32 + kg*8]);
            bf16x8 b0 = *reinterpret_cast<const bf16x8*>(WoT + (size_t)((wv*4+0)*16 + lr)*DD + ks*32 + kg*8);
            bf16x8 b1 = *reinterpret_cast<const bf16x8*>(WoT + (size_t)((wv*4+1)*16 + lr)*DD + ks*32 + kg*8);
            bf16x8 b2 = *reinterpret_cast<const bf16x8*>(WoT + (size_t)((wv*4+2)*16 + lr)*DD + ks*32 + kg*8);
            bf16x8 b3 = *reinterpret_cast<const bf16x8*>(WoT + (size_t)((wv*4+3)*16 + lr)*DD + ks*32 + kg*8);
            acc0 = __builtin_amdgcn_mfma_f32_16x16x32_bf16(a, b0, acc0, 0,0,0);
            acc1 = __builtin_amdgcn_mfma_f32_16x16x32_bf16(a, b1, acc1, 0,0,0);
            acc2 = __builtin_amdgcn_mfma_f32_16x16x32_bf16(a, b2, acc2, 0,0,0);
            acc3 = __builtin_amdgcn_mfma_f32_16x16x32_bf16(a, b3, acc3, 0,0,0);
        }
        #pragma unroll
        for(int rg=0; rg<4; rg++){
            int i = kg*4 + rg;
            fbo[i][(wv*4+0)*16 + lr] = acc0[rg];
            fbo[i][(wv*4+1)*16 + lr] = acc1[rg];
            fbo[i][(wv*4+2)*16 + lr] = acc2[rg];
            fbo[i][(wv*4+3)*16 + lr] = acc3[rg];
        }
    }
    __syncthreads();

    // residual + LN (thread t = col)
    float accr[16];
    float bb = bo[t];
    #pragma unroll
    for(int r=0;r<16;r++) accr[r] = fbo[r][t] + bb + x[((size_t)r0+r)*DD + t];
    __syncthreads();
    #pragma unroll
    for(int r=0;r<16;r++) fbo[r][t] = accr[r];
    __syncthreads();
    {
        int rr = t>>4, seg = t&15;
        float s=0.f, sqs=0.f;
        #pragma unroll
        for(int e=0;e<16;e++){
            float y = fbo[rr][seg*16+e];
            s += y; sqs += y*y;
        }
        ps[rr][seg][0]=s; ps[rr][seg][1]=sqs;
    }
    __syncthreads();
    if(t<16){
        float s=0.f, sqs=0.f;
        #pragma unroll
        for(int e=0;e<16;e++){ s+=ps[t][e][0]; sqs+=ps[t][e][1]; }
        float mu = s/256.f;
        float var = sqs/256.f - mu*mu;
        muL[t]=mu; rsL[t]=rsqrtf(var+EPS);
    }
    __syncthreads();
    float gg = g[t], bl = bln[t];
    #pragma unroll
    for(int r=0;r<16;r++){
        out[((size_t)r0+r)*DD + t] = (accr[r]-muL[r])*rsL[r]*gg + bl;
    }
}

extern "C" void kernel_launch(void* const* d_in, const int* in_sizes, int n_in,
                              void* d_out, int out_size, void* d_ws, size_t ws_size,
                              hipStream_t stream) {
    const float* x    = (const float*)d_in[0];
    const int*   adj  = (const int*)d_in[1];
    const float* Wq   = (const float*)d_in[2];
    const float* bq   = (const float*)d_in[3];
    const float* Wk   = (const float*)d_in[4];
    const float* bk   = (const float*)d_in[5];
    const float* Wv   = (const float*)d_in[6];
    const float* bv   = (const float*)d_in[7];
    const float* aa   = (const float*)d_in[8];
    const float* Wo   = (const float*)d_in[9];
    const float* bo   = (const float*)d_in[10];
    const float* lng  = (const float*)d_in[11];
    const float* lnb  = (const float*)d_in[12];

    float* out0  = (float*)d_out;                  // (B,N,D)
    float* meanw = out0 + (size_t)BB*NN*DD;        // (B,N,N)

    char* wsb = (char*)d_ws;
    float* cq   = (float*)wsb;                                    // 16
    float* ck   = cq + 16;                                        // 16
    float* Mk   = ck + 16;                                        // 16 (+pad)
    float* sqv  = Mk + 80;                                        // 32768
    float* skH  = sqv + 32768;                                    // 32768
    float* Madj = skH + 32768;                                    // 32768
    unsigned* adjm = (unsigned*)(Madj + 32768);                   // BB*NN*64 u32 = 1MB
    ushort* uqkb= (ushort*)(adjm + (size_t)BB*NN*64);             // 16*256 u16
    ushort* WoT = uqkb + 16*DD;                                   // 256*256 u16
    ushort* WvT = WoT + (size_t)DD*DD;                            // 256*256 u16
    ushort* vT  = WvT + (size_t)DD*DD;                            // BB*DD*NN u16
    ushort* attp= vT + (size_t)BB*DD*NN;                          // JC*BB*NN*DD u16

    k_prep<<<136, 256, 0, stream>>>(Wq, bq, Wk, bk, aa, Wo, Wv, uqkb, cq, ck, WoT, WvT);
    k_sqskv<<<(BB*NN)/16, 256, 0, stream>>>(x, bv, uqkb, WvT, cq, ck, vT, sqv, skH);
    k_maxsk<<<BB*HH, 256, 0, stream>>>(skH, Mk);
    k_denom<<<(BB*NN)/4, 256, 0, stream>>>(adj, sqv, skH, Mk, Madj, adjm);
    k_attn<<<dim3(NN/TI, BB, JC), 256, 0, stream>>>(adjm, sqv, skH, Madj, vT, meanw, attp);
    k_out<<<(BB*NN)/16, 256, 0, stream>>>(attp, x, WoT, bo, lng, lnb, out0);
}

// Round 24
// 89.120 us; speedup vs baseline: 1.0641x; 1.0641x over previous
//
#include <hip/hip_runtime.h>

#define BB 2
#define NN 2048
#define DD 256
#define HH 8
#define HD 32
#define EPS 1e-5f
#define L2E 1.4426950408889634f

typedef __attribute__((ext_vector_type(8))) short bf16x8;
typedef __attribute__((ext_vector_type(4))) float f32x4;
typedef __attribute__((ext_vector_type(2))) float f32x2;
typedef __attribute__((ext_vector_type(8))) unsigned short u16x8;

__device__ __forceinline__ float lky(float z){ return fmaxf(z, 0.2f*z); }

// Raw hardware exp2: args <= ~0 here; flush-to-zero below -126 is the right answer.
__device__ __forceinline__ float exp2raw(float x){
    float r;
    asm("v_exp_f32 %0, %1" : "=v"(r) : "v"(x));
    return r;
}

__device__ __forceinline__ ushort f2bf(float f){
    union{ float f; unsigned u; } c; c.f = f;
    unsigned r = c.u + 0x7fffu + ((c.u >> 16) & 1u);
    return (ushort)(r >> 16);
}
__device__ __forceinline__ float bf2f(ushort u){
    union{ unsigned u; float f; } c; c.u = ((unsigned)u) << 16; return c.f;
}
__device__ __forceinline__ unsigned cvtpk(float lo, float hi){
    unsigned r;
    asm("v_cvt_pk_bf16_f32 %0, %1, %2" : "=v"(r) : "v"(lo), "v"(hi));
    return r;
}

// K0: blocks 0-7: uqkb bf16 + cq/ck (log2e-scaled); 8-71: WoT; 72-135: WvT.
__global__ void k_prep(const float* __restrict__ Wq, const float* __restrict__ bq,
                       const float* __restrict__ Wk, const float* __restrict__ bk,
                       const float* __restrict__ aa, const float* __restrict__ Wo,
                       const float* __restrict__ Wv,
                       ushort* __restrict__ uqkb, float* __restrict__ cq,
                       float* __restrict__ ck, ushort* __restrict__ WoT,
                       ushort* __restrict__ WvT){
    int t = threadIdx.x;
    if(blockIdx.x < 8){
        int h = blockIdx.x;
        int d = t;
        float accq = 0.f, acck = 0.f;
        #pragma unroll
        for(int k=0; k<HD; k++){
            accq += Wq[(size_t)d*DD + h*HD + k] * aa[h*2*HD + k];
            acck += Wk[(size_t)d*DD + h*HD + k] * aa[h*2*HD + HD + k];
        }
        uqkb[h*DD + d]     = f2bf(accq * L2E);
        uqkb[(8+h)*DD + d] = f2bf(acck * L2E);
        __shared__ float red[64];
        if(d < HD){
            red[d]      = bq[h*HD+d]*aa[h*2*HD+d];
            red[32+d]   = bk[h*HD+d]*aa[h*2*HD+HD+d];
        }
        __syncthreads();
        if(d==0){ float s=0.f; for(int k=0;k<32;k++) s+=red[k];    cq[h]=s*L2E; }
        if(d==1){ float s=0.f; for(int k=0;k<32;k++) s+=red[32+k]; ck[h]=s*L2E; }
    } else if(blockIdx.x < 72){
        int blk = blockIdx.x - 8;     // 0..63
        int wv = t>>6, l = t&63;
        int tile = blk*4 + wv;        // 0..255
        int tr = (tile>>4)*16, tc = (tile&15)*16;
        #pragma unroll
        for(int e=0;e<4;e++){
            int idx = l*4+e;
            int kk = tr + (idx>>4);
            int nn = tc + (idx&15);
            WoT[(size_t)nn*DD + kk] = f2bf(Wo[(size_t)kk*DD + nn]);
        }
    } else {
        int blk = blockIdx.x - 72;    // 0..63
        int wv = t>>6, l = t&63;
        int tile = blk*4 + wv;
        int tr = (tile>>4)*16, tc = (tile&15)*16;
        #pragma unroll
        for(int e=0;e<4;e++){
            int idx = l*4+e;
            int kk = tr + (idx>>4);
            int nn = tc + (idx&15);
            WvT[(size_t)nn*DD + kk] = f2bf(Wv[(size_t)kk*DD + nn]);
        }
    }
}

// K1: 16 rows/block, full MFMA: scores (wave0) + v-projection GEMM (all waves).
__global__ __launch_bounds__(256, 4)
void k_sqskv(const float* __restrict__ x, const float* __restrict__ bv,
             const ushort* __restrict__ uqkb, const ushort* __restrict__ WvT,
             const float* __restrict__ cq, const float* __restrict__ ck,
             ushort* __restrict__ vT, float* __restrict__ sq,
             float* __restrict__ skH){
    __shared__ ushort xb[16][264];   // bf16 x rows
    int t = threadIdx.x;
    int r0 = blockIdx.x * 16;
    int b  = r0 >> 11;
    int j0 = r0 & (NN-1);
    #pragma unroll
    for(int i=0;i<16;i++) xb[i][t] = f2bf(x[((size_t)r0+i)*DD + t]);
    __syncthreads();

    int wv = t>>6, l = t&63, lr = l&15, kg = l>>4;

    // wave 0: scores: C[i][n] = sum_k xb[i][k]*uqkb[n][k]  (M=16 real rows)
    if(wv == 0){
        f32x4 acc = (f32x4){0.f,0.f,0.f,0.f};
        #pragma unroll
        for(int ks=0; ks<8; ks++){
            bf16x8 a = *reinterpret_cast<const bf16x8*>(&xb[lr][ks*32 + kg*8]);
            bf16x8 bb = *reinterpret_cast<const bf16x8*>(uqkb + (size_t)lr*DD + ks*32 + kg*8);
            acc = __builtin_amdgcn_mfma_f32_16x16x32_bf16(a, bb, acc, 0,0,0);
        }
        #pragma unroll
        for(int rg=0; rg<4; rg++){
            int i = kg*4 + rg;
            int R = r0 + i;
            float vsc = acc[rg];
            if(lr < 8) sq[(size_t)R*HH + lr] = vsc + cq[lr];
            else       skH[((size_t)b*NN + (R & (NN-1)))*HH + (lr-8)] = vsc + ck[lr-8];
        }
    }

    // v GEMM: wave wv -> n-tiles 4wv..4wv+3; C[i][n]; store vT[b][n][j0+i]
    f32x4 vacc[4];
    #pragma unroll
    for(int q=0;q<4;q++) vacc[q] = (f32x4){0.f,0.f,0.f,0.f};
    #pragma unroll
    for(int ks=0; ks<8; ks++){
        bf16x8 a = *reinterpret_cast<const bf16x8*>(&xb[lr][ks*32 + kg*8]);
        #pragma unroll
        for(int q=0;q<4;q++){
            int n0 = (wv*4+q)*16;
            bf16x8 bb = *reinterpret_cast<const bf16x8*>(WvT + (size_t)(n0+lr)*DD + ks*32 + kg*8);
            vacc[q] = __builtin_amdgcn_mfma_f32_16x16x32_bf16(a, bb, vacc[q], 0,0,0);
        }
    }
    #pragma unroll
    for(int q=0;q<4;q++){
        int n = (wv*4+q)*16 + lr;
        float bvn = bv[n];
        ushort4 pk;
        pk.x = f2bf(vacc[q][0] + bvn);
        pk.y = f2bf(vacc[q][1] + bvn);
        pk.z = f2bf(vacc[q][2] + bvn);
        pk.w = f2bf(vacc[q][3] + bvn);
        *reinterpret_cast<ushort4*>(&vT[((size_t)b*DD + n)*NN + j0 + kg*4]) = pk;
    }
}

// K1b: Mk[b][h] = max_j skH[b][j][h]
__global__ void k_maxsk(const float* __restrict__ skH, float* __restrict__ Mk){
    int b = blockIdx.x >> 3, h = blockIdx.x & 7;
    int t = threadIdx.x;
    float m = -1e30f;
    for(int j=t; j<NN; j+=256) m = fmaxf(m, skH[((size_t)b*NN + j)*HH + h]);
    #pragma unroll
    for(int off=32; off>=1; off>>=1) m = fmaxf(m, __shfl_xor(m, off));
    __shared__ float red[4];
    if((t&63)==0) red[t>>6] = m;
    __syncthreads();
    if(t==0) Mk[blockIdx.x] = fmaxf(fmaxf(red[0],red[1]), fmaxf(red[2],red[3]));
}

// K2: 2 rows/block, raw adj in, Madj + adj-bitmask out (pack free — adj already read here)
__global__ void k_denom(const int* __restrict__ adj, const float* __restrict__ sq,
                        const float* __restrict__ skH, const float* __restrict__ Mk,
                        float* __restrict__ Madj, unsigned* __restrict__ adjm){
    int r0 = blockIdx.x*2;          // rows r0, r0+1 (same b)
    int b = r0 >> 11;
    int t = threadIdx.x;
    int w = t>>6, l = t&63;
    float sq1[HH], sq2[HH], M1[HH], M2[HH], s1[HH], s2[HH];
    {
        float4 a0 = *reinterpret_cast<const float4*>(&sq[(size_t)r0*HH]);
        float4 a1 = *reinterpret_cast<const float4*>(&sq[(size_t)r0*HH+4]);
        float4 b0 = *reinterpret_cast<const float4*>(&sq[(size_t)(r0+1)*HH]);
        float4 b1 = *reinterpret_cast<const float4*>(&sq[(size_t)(r0+1)*HH+4]);
        float4 m0 = *reinterpret_cast<const float4*>(&Mk[b*HH]);
        float4 m1 = *reinterpret_cast<const float4*>(&Mk[b*HH+4]);
        sq1[0]=a0.x; sq1[1]=a0.y; sq1[2]=a0.z; sq1[3]=a0.w;
        sq1[4]=a1.x; sq1[5]=a1.y; sq1[6]=a1.z; sq1[7]=a1.w;
        sq2[0]=b0.x; sq2[1]=b0.y; sq2[2]=b0.z; sq2[3]=b0.w;
        sq2[4]=b1.x; sq2[5]=b1.y; sq2[6]=b1.z; sq2[7]=b1.w;
        float mk[8] = {m0.x,m0.y,m0.z,m0.w,m1.x,m1.y,m1.z,m1.w};
        #pragma unroll
        for(int h=0;h<HH;h++){
            M1[h] = lky(sq1[h]+mk[h]); M2[h] = lky(sq2[h]+mk[h]);
            s1[h]=0.f; s2[h]=0.f;
        }
    }
    const int* arow1 = adj + (size_t)r0*NN;
    const int* arow2 = adj + ((size_t)r0+1)*NN;
    for(int j0=0; j0<NN; j0+=256){
        int j = j0 + t;
        int a1 = arow1[j];
        int a2 = arow2[j];
        {
            unsigned long long m1b = __ballot(a1 != 0);
            unsigned long long m2b = __ballot(a2 != 0);
            int cw = (j0 >> 5) + w*2;
            if(l == 0){
                adjm[(size_t)r0*64 + cw]       = (unsigned)m1b;
                adjm[((size_t)r0+1)*64 + cw]   = (unsigned)m2b;
            }
            if(l == 32){
                adjm[(size_t)r0*64 + cw + 1]     = (unsigned)(m1b >> 32);
                adjm[((size_t)r0+1)*64 + cw + 1] = (unsigned)(m2b >> 32);
            }
        }
        float4 v0 = *reinterpret_cast<const float4*>(&skH[((size_t)b*NN + j)*HH]);
        float4 v1 = *reinterpret_cast<const float4*>(&skH[((size_t)b*NN + j)*HH+4]);
        float sk[8] = {v0.x,v0.y,v0.z,v0.w,v1.x,v1.y,v1.z,v1.w};
        #pragma unroll
        for(int h=0; h<HH; h++){
            float e1 = exp2raw(lky(sq1[h]+sk[h]) - M1[h]);
            float e2 = exp2raw(lky(sq2[h]+sk[h]) - M2[h]);
            s1[h] += a1 ? e1 : 0.f;
            s2[h] += a2 ? e2 : 0.f;
        }
    }
    #pragma unroll
    for(int h=0;h<HH;h++){
        #pragma unroll
        for(int off=32; off>=1; off>>=1){
            s1[h] += __shfl_xor(s1[h], off);
            s2[h] += __shfl_xor(s2[h], off);
        }
    }
    __shared__ float red[4][16];
    if(l==0){
        #pragma unroll
        for(int h=0;h<HH;h++){ red[w][h]=s1[h]; red[w][8+h]=s2[h]; }
    }
    __syncthreads();
    if(t < 16){
        float s = red[0][t]+red[1][t]+red[2][t]+red[3][t];
        int h = t & 7;
        if(t < 8) Madj[(size_t)r0*HH + h]     = M1[h] + log2f(s);
        else      Madj[((size_t)r0+1)*HH + h] = M2[h] + log2f(s);
    }
}

// K3: verified structure; JC=4.
#define TI 32
#define JT 32
#define JC 4
#define JPC (NN/JC)   // 512

__global__ __launch_bounds__(256, 4)
void k_attn(const unsigned* __restrict__ adjm, const float* __restrict__ sq,
            const float* __restrict__ skH, const float* __restrict__ Madj,
            const ushort* __restrict__ vT, float* __restrict__ meanw,
            ushort* __restrict__ attp){
    __shared__ __align__(16) char smem[40960];
    ushort (*wLDS)[TI][40] = (ushort (*)[TI][40])smem;           // [h][i][j] 20480B
    ushort (*vLDS)[40]     = (ushort (*)[40])(smem + 20480);     // [d][j]    20480B
    float* fb = (float*)smem;                                     // epilogue 32KB

    int t  = threadIdx.x;
    int it = blockIdx.x;
    int b  = blockIdx.y;
    int jc = blockIdx.z;
    int i0 = it*TI;
    int R0 = b*NN + i0;

    int ia = t >> 4;
    int jp = t & 15;
    int jj = jp*2;

    float sq1[8], sq2[8], M1[8], M2[8];
    {
        float4 a0 = *reinterpret_cast<const float4*>(&sq[(size_t)(R0+ia)*HH]);
        float4 a1 = *reinterpret_cast<const float4*>(&sq[(size_t)(R0+ia)*HH+4]);
        float4 b0 = *reinterpret_cast<const float4*>(&sq[(size_t)(R0+16+ia)*HH]);
        float4 b1 = *reinterpret_cast<const float4*>(&sq[(size_t)(R0+16+ia)*HH+4]);
        sq1[0]=a0.x; sq1[1]=a0.y; sq1[2]=a0.z; sq1[3]=a0.w;
        sq1[4]=a1.x; sq1[5]=a1.y; sq1[6]=a1.z; sq1[7]=a1.w;
        sq2[0]=b0.x; sq2[1]=b0.y; sq2[2]=b0.z; sq2[3]=b0.w;
        sq2[4]=b1.x; sq2[5]=b1.y; sq2[6]=b1.z; sq2[7]=b1.w;
        float4 c0 = *reinterpret_cast<const float4*>(&Madj[(size_t)(R0+ia)*HH]);
        float4 c1 = *reinterpret_cast<const float4*>(&Madj[(size_t)(R0+ia)*HH+4]);
        float4 d0 = *reinterpret_cast<const float4*>(&Madj[(size_t)(R0+16+ia)*HH]);
        float4 d1 = *reinterpret_cast<const float4*>(&Madj[(size_t)(R0+16+ia)*HH+4]);
        M1[0]=c0.x; M1[1]=c0.y; M1[2]=c0.z; M1[3]=c0.w;
        M1[4]=c1.x; M1[5]=c1.y; M1[6]=c1.z; M1[7]=c1.w;
        M2[0]=d0.x; M2[1]=d0.y; M2[2]=d0.z; M2[3]=d0.w;
        M2[4]=d1.x; M2[5]=d1.y; M2[6]=d1.z; M2[7]=d1.w;
    }

    int wid = t >> 6;
    int l   = t & 63;
    int lr  = l & 15;
    int kg  = l >> 4;

    f32x4 acc[2][2][2];
    #pragma unroll
    for(int hh=0;hh<2;hh++)
        #pragma unroll
        for(int mi=0;mi<2;mi++)
            #pragma unroll
            for(int ni=0;ni<2;ni++) acc[hh][mi][ni] = (f32x4){0.f,0.f,0.f,0.f};

    const ushort* vsrc = vT + ((size_t)b*DD + t)*NN;
    const float* skbase = skH + (size_t)b*NN*HH;
    const unsigned* mArow = adjm + (size_t)(R0+ia)*64 + jc*16;
    const unsigned* mBrow = adjm + (size_t)(R0+16+ia)*64 + jc*16;

    for(int jt=0; jt<JPC/JT; jt++){
        int jb = jc*JPC + jt*JT;

        __syncthreads();   // prev tile MFMA done reading wLDS/vLDS

        // stage v to LDS (loads AFTER barrier — proven placement)
        {
            const ushort* src = vsrc + jb;
            u16x8 v0 = *reinterpret_cast<const u16x8*>(src);
            u16x8 v1 = *reinterpret_cast<const u16x8*>(src+8);
            u16x8 v2 = *reinterpret_cast<const u16x8*>(src+16);
            u16x8 v3 = *reinterpret_cast<const u16x8*>(src+24);
            *reinterpret_cast<u16x8*>(&vLDS[t][0])  = v0;
            *reinterpret_cast<u16x8*>(&vLDS[t][8])  = v1;
            *reinterpret_cast<u16x8*>(&vLDS[t][16]) = v2;
            *reinterpret_cast<u16x8*>(&vLDS[t][24]) = v3;
        }

        // Phase A
        {
            float4 p0 = *reinterpret_cast<const float4*>(&skbase[(size_t)(jb+jj)*HH]);
            float4 p1 = *reinterpret_cast<const float4*>(&skbase[(size_t)(jb+jj)*HH+4]);
            float4 q0 = *reinterpret_cast<const float4*>(&skbase[(size_t)(jb+jj+1)*HH]);
            float4 q1 = *reinterpret_cast<const float4*>(&skbase[(size_t)(jb+jj+1)*HH+4]);
            unsigned wA = mArow[jt];
            unsigned wB = mBrow[jt];
            float ska[8] = {p0.x,p0.y,p0.z,p0.w,p1.x,p1.y,p1.z,p1.w};
            float skb[8] = {q0.x,q0.y,q0.z,q0.w,q1.x,q1.y,q1.z,q1.w};
            unsigned bA = (wA >> jj) & 3u;
            unsigned bB = (wB >> jj) & 3u;
            f32x2 wsA = {0.f,0.f}, wsB = {0.f,0.f};
            #pragma unroll
            for(int h=0; h<HH; h++){
                float eA0 = exp2raw(lky(sq1[h]+ska[h]) - M1[h]);
                float eA1 = exp2raw(lky(sq1[h]+skb[h]) - M1[h]);
                float eB0 = exp2raw(lky(sq2[h]+ska[h]) - M2[h]);
                float eB1 = exp2raw(lky(sq2[h]+skb[h]) - M2[h]);
                float w00 = (bA&1u) ? eA0 : 0.f;
                float w01 = (bA&2u) ? eA1 : 0.f;
                float w10 = (bB&1u) ? eB0 : 0.f;
                float w11 = (bB&2u) ? eB1 : 0.f;
                wsA += (f32x2){w00, w01};
                wsB += (f32x2){w10, w11};
                *reinterpret_cast<unsigned*>(&wLDS[h][ia][jj])    = cvtpk(w00, w01);
                *reinterpret_cast<unsigned*>(&wLDS[h][16+ia][jj]) = cvtpk(w10, w11);
            }
            wsA *= 0.125f; wsB *= 0.125f;
            *reinterpret_cast<f32x2*>(&meanw[((size_t)(R0+ia))*NN + jb + jj])    = wsA;
            *reinterpret_cast<f32x2*>(&meanw[((size_t)(R0+16+ia))*NN + jb + jj]) = wsB;
        }
        __syncthreads();

        // Phase B: MFMA
        #pragma unroll
        for(int hh=0; hh<2; hh++){
            int h = wid*2 + hh;
            bf16x8 a0 = *reinterpret_cast<const bf16x8*>(&wLDS[h][lr][kg*8]);
            bf16x8 a1 = *reinterpret_cast<const bf16x8*>(&wLDS[h][16+lr][kg*8]);
            bf16x8 b0 = *reinterpret_cast<const bf16x8*>(&vLDS[h*HD + lr][kg*8]);
            bf16x8 b1 = *reinterpret_cast<const bf16x8*>(&vLDS[h*HD + 16 + lr][kg*8]);
            acc[hh][0][0] = __builtin_amdgcn_mfma_f32_16x16x32_bf16(a0, b0, acc[hh][0][0], 0,0,0);
            acc[hh][0][1] = __builtin_amdgcn_mfma_f32_16x16x32_bf16(a0, b1, acc[hh][0][1], 0,0,0);
            acc[hh][1][0] = __builtin_amdgcn_mfma_f32_16x16x32_bf16(a1, b0, acc[hh][1][0], 0,0,0);
            acc[hh][1][1] = __builtin_amdgcn_mfma_f32_16x16x32_bf16(a1, b1, acc[hh][1][1], 0,0,0);
        }
    }

    // Epilogue: XOR-swizzled fb, coalesced bf16 stores
    __syncthreads();
    #pragma unroll
    for(int hh=0;hh<2;hh++)
        #pragma unroll
        for(int mi=0;mi<2;mi++)
            #pragma unroll
            for(int ni=0;ni<2;ni++)
                #pragma unroll
                for(int rg=0; rg<4; rg++){
                    int i = mi*16 + kg*4 + rg;
                    int d = (wid*2+hh)*HD + ni*16 + lr;
                    fb[i*256 + (d ^ ((i&7)<<2))] = acc[hh][mi][ni][rg];
                }
    __syncthreads();
    {
        int i  = t >> 3;              // 0..31 row; 8 threads per row
        int d0 = (t & 7) * 32;        // contiguous 512B per row across 8 threads
        int swz = (i & 7) << 2;
        size_t orow = ((size_t)(jc*BB + b)*NN + i0 + i)*DD + d0;
        #pragma unroll
        for(int qq=0; qq<4; qq++){
            float4 f0 = *reinterpret_cast<const float4*>(&fb[i*256 + ((d0 + qq*8)     ^ swz)]);
            float4 f1 = *reinterpret_cast<const float4*>(&fb[i*256 + ((d0 + qq*8 + 4) ^ swz)]);
            uint4 pk;
            pk.x = cvtpk(f0.x, f0.y); pk.y = cvtpk(f0.z, f0.w);
            pk.z = cvtpk(f1.x, f1.y); pk.w = cvtpk(f1.z, f1.w);
            *reinterpret_cast<uint4*>(&attp[orow + qq*8]) = pk;
        }
    }
}

// K4: out = LN( (sum attp) @ Wo + bo + x ) — MFMA GEMM, 16 real rows/block.
__global__ __launch_bounds__(256, 2)
void k_out(const ushort* __restrict__ attp, const float* __restrict__ x,
           const ushort* __restrict__ WoT, const float* __restrict__ bo,
           const float* __restrict__ g, const float* __restrict__ bln,
           float* __restrict__ out){
    __shared__ ushort ab[16][264];   // bf16 attended, 16 real rows
    __shared__ float fbo[16][260];   // GEMM result / LN scratch
    __shared__ float ps[16][16][2];
    __shared__ float muL[16], rsL[16];
    int t = threadIdx.x;
    int r0 = blockIdx.x*16;
    int b  = r0 >> 11;
    int j0 = r0 & (NN-1);

    // sum partials -> ab bf16 (two row-groups of 8)
    #pragma unroll
    for(int rp=0; rp<2; rp++){
        int rr = rp*8 + (t >> 5);
        int d0 = (t & 31) * 8;
        float s8[8];
        #pragma unroll
        for(int e=0;e<8;e++) s8[e]=0.f;
        #pragma unroll
        for(int jc=0; jc<JC; jc++){
            u16x8 v = *reinterpret_cast<const u16x8*>(&attp[((size_t)(jc*BB + b)*NN + j0 + rr)*DD + d0]);
            #pragma unroll
            for(int e=0;e<8;e++) s8[e] += bf2f(v[e]);
        }
        u16x8 pack;
        #pragma unroll
        for(int e=0;e<8;e++) pack[e] = f2bf(s8[e]);
        *reinterpret_cast<u16x8*>(&ab[rr][d0]) = pack;
    }
    __syncthreads();

    // MFMA GEMM: wave wv handles n-tiles 4wv..4wv+3, M=16 all-real
    {
        int wv = t>>6, l = t&63, lr = l&15, kg = l>>4;
        f32x4 acc0 = (f32x4){0.f,0.f,0.f,0.f};
        f32x4 acc1 = (f32x4){0.f,0.f,0.f,0.f};
        f32x4 acc2 = (f32x4){0.f,0.f,0.f,0.f};
        f32x4 acc3 = (f32x4){0.f,0.f,0.f,0.f};
        #pragma unroll
        for(int ks=0; ks<8; ks++){
            bf16x8 a = *reinterpret_cast<const bf16x8*>(&ab[lr][ks*32 + kg*8]);
            bf16x8 b0 = *reinterpret_cast<const bf16x8*>(WoT + (size_t)((wv*4+0)*16 + lr)*DD + ks*32 + kg*8);
            bf16x8 b1 = *reinterpret_cast<const bf16x8*>(WoT + (size_t)((wv*4+1)*16 + lr)*DD + ks*32 + kg*8);
            bf16x8 b2 = *reinterpret_cast<const bf16x8*>(WoT + (size_t)((wv*4+2)*16 + lr)*DD + ks*32 + kg*8);
            bf16x8 b3 = *reinterpret_cast<const bf16x8*>(WoT + (size_t)((wv*4+3)*16 + lr)*DD + ks*32 + kg*8);
            acc0 = __builtin_amdgcn_mfma_f32_16x16x32_bf16(a, b0, acc0, 0,0,0);
            acc1 = __builtin_amdgcn_mfma_f32_16x16x32_bf16(a, b1, acc1, 0,0,0);
            acc2 = __builtin_amdgcn_mfma_f32_16x16x32_bf16(a, b2, acc2, 0,0,0);
            acc3 = __builtin_amdgcn_mfma_f32_16x16x32_bf16(a, b3, acc3, 0,0,0);
        }
        #pragma unroll
        for(int rg=0; rg<4; rg++){
            int i = kg*4 + rg;
            fbo[i][(wv*4+0)*16 + lr] = acc0[rg];
            fbo[i][(wv*4+1)*16 + lr] = acc1[rg];
            fbo[i][(wv*4+2)*16 + lr] = acc2[rg];
            fbo[i][(wv*4+3)*16 + lr] = acc3[rg];
        }
    }
    __syncthreads();

    // residual + LN (thread t = col)
    float accr[16];
    float bb = bo[t];
    #pragma unroll
    for(int r=0;r<16;r++) accr[r] = fbo[r][t] + bb + x[((size_t)r0+r)*DD + t];
    __syncthreads();
    #pragma unroll
    for(int r=0;r<16;r++) fbo[r][t] = accr[r];
    __syncthreads();
    {
        int rr = t>>4, seg = t&15;
        float s=0.f, sqs=0.f;
        #pragma unroll
        for(int e=0;e<16;e++){
            float y = fbo[rr][seg*16+e];
            s += y; sqs += y*y;
        }
        ps[rr][seg][0]=s; ps[rr][seg][1]=sqs;
    }
    __syncthreads();
    if(t<16){
        float s=0.f, sqs=0.f;
        #pragma unroll
        for(int e=0;e<16;e++){ s+=ps[t][e][0]; sqs+=ps[t][e][1]; }
        float mu = s/256.f;
        float var = sqs/256.f - mu*mu;
        muL[t]=mu; rsL[t]=rsqrtf(var+EPS);
    }
    __syncthreads();
    float gg = g[t], bl = bln[t];
    #pragma unroll
    for(int r=0;r<16;r++){
        out[((size_t)r0+r)*DD + t] = (accr[r]-muL[r])*rsL[r]*gg + bl;
    }
}

extern "C" void kernel_launch(void* const* d_in, const int* in_sizes, int n_in,
                              void* d_out, int out_size, void* d_ws, size_t ws_size,
                              hipStream_t stream) {
    const float* x    = (const float*)d_in[0];
    const int*   adj  = (const int*)d_in[1];
    const float* Wq   = (const float*)d_in[2];
    const float* bq   = (const float*)d_in[3];
    const float* Wk   = (const float*)d_in[4];
    const float* bk   = (const float*)d_in[5];
    const float* Wv   = (const float*)d_in[6];
    const float* bv   = (const float*)d_in[7];
    const float* aa   = (const float*)d_in[8];
    const float* Wo   = (const float*)d_in[9];
    const float* bo   = (const float*)d_in[10];
    const float* lng  = (const float*)d_in[11];
    const float* lnb  = (const float*)d_in[12];

    float* out0  = (float*)d_out;                  // (B,N,D)
    float* meanw = out0 + (size_t)BB*NN*DD;        // (B,N,N)

    char* wsb = (char*)d_ws;
    float* cq   = (float*)wsb;                                    // 16
    float* ck   = cq + 16;                                        // 16
    float* Mk   = ck + 16;                                        // 16 (+pad)
    float* sqv  = Mk + 80;                                        // 32768
    float* skH  = sqv + 32768;                                    // 32768
    float* Madj = skH + 32768;                                    // 32768
    unsigned* adjm = (unsigned*)(Madj + 32768);                   // BB*NN*64 u32 = 1MB
    ushort* uqkb= (ushort*)(adjm + (size_t)BB*NN*64);             // 16*256 u16
    ushort* WoT = uqkb + 16*DD;                                   // 256*256 u16
    ushort* WvT = WoT + (size_t)DD*DD;                            // 256*256 u16
    ushort* vT  = WvT + (size_t)DD*DD;                            // BB*DD*NN u16
    ushort* attp= vT + (size_t)BB*DD*NN;                          // JC*BB*NN*DD u16

    k_prep<<<136, 256, 0, stream>>>(Wq, bq, Wk, bk, aa, Wo, Wv, uqkb, cq, ck, WoT, WvT);
    k_sqskv<<<(BB*NN)/16, 256, 0, stream>>>(x, bv, uqkb, WvT, cq, ck, vT, sqv, skH);
    k_maxsk<<<BB*HH, 256, 0, stream>>>(skH, Mk);
    k_denom<<<(BB*NN)/2, 256, 0, stream>>>(adj, sqv, skH, Mk, Madj, adjm);
    k_attn<<<dim3(NN/TI, BB, JC), 256, 0, stream>>>(adjm, sqv, skH, Madj, vT, meanw, attp);
    k_out<<<(BB*NN)/16, 256, 0, stream>>>(attp, x, WoT, bo, lng, lnb, out0);
}